// Round 11
// baseline (379.849 us; speedup 1.0000x reference)
//
#include <hip/hip_runtime.h>
#include <cstdint>
#include <cstddef>

// Problem constants (fixed by the reference)
#define NN 16384      // nodes
#define DIN 1024      // hid_size
#define DMID 1500     // hidden_size (logical)
#define DMIDP 1536    // padded to multiple of 128
#define NE 131072     // edges

typedef __bf16 bf16;
typedef __bf16 bf16x4 __attribute__((ext_vector_type(4)));
typedef __bf16 bf16x8 __attribute__((ext_vector_type(8)));
typedef float f32x4 __attribute__((ext_vector_type(4)));

#define GLOBAL_AS __attribute__((address_space(1)))
#define LDS_AS __attribute__((address_space(3)))

__device__ __forceinline__ void gload_lds16(const bf16* g, bf16* l) {
    // async 16B/lane global->LDS; LDS dest is wave-uniform base + lane*16
    __builtin_amdgcn_global_load_lds((GLOBAL_AS const unsigned int*)(g),
                                     (LDS_AS unsigned int*)(l), 16, 0, 0);
}

// ---------------- fused prep: cvt_x + cvt_w1 + cvt_w2 + zero_cnt ----------------
// R9-proven fusion. R11: cvt_x grid-strided x4 (4096 blocks instead of 16384
// one-float4-per-thread blocks; each pass coalesced).
#define CVX_BLOCKS (NN * DIN / 4 / 1024)         // 4096 (4 float4 / thread)
#define CW1_BLOCKS ((DMIDP / 32) * (DIN / 32))   // 1536
#define CW2_BLOCKS ((DIN / 32) * (DMIDP / 32))   // 1536
#define ZERO_BLOCKS (NN / 256)                   // 64
#define PREP_BLOCKS (CVX_BLOCKS + CW1_BLOCKS + CW2_BLOCKS + ZERO_BLOCKS)

__global__ __launch_bounds__(256) void k_prep(const float4* __restrict__ x,
                                              bf16x4* __restrict__ xb,
                                              const float* __restrict__ W1,
                                              bf16* __restrict__ W1b,
                                              const float* __restrict__ W2,
                                              bf16* __restrict__ W2b,
                                              int* __restrict__ cnt) {
    __shared__ float t[32][33];
    int b = blockIdx.x;
    if (b < CVX_BLOCKS) {
        // cvt_x: f32 -> bf16, 4 coalesced passes per thread
#pragma unroll
        for (int p = 0; p < 4; ++p) {
            int i = b * 1024 + p * 256 + threadIdx.x;
            float4 v = x[i];
            bf16x4 o;
            o[0] = (bf16)v.x; o[1] = (bf16)v.y; o[2] = (bf16)v.z; o[3] = (bf16)v.w;
            xb[i] = o;
        }
        return;
    }
    b -= CVX_BLOCKS;
    if (b < CW1_BLOCKS) {
        // W1 [1024][1500] f32 -> W1b [1536][1024] bf16 (transposed, n-pad 0)
        int n0 = (b % (DMIDP / 32)) * 32;
        int k0 = (b / (DMIDP / 32)) * 32;
        int tx = threadIdx.x & 31, ty = threadIdx.x >> 5;
#pragma unroll
        for (int p = 0; p < 4; ++p) {
            int n = n0 + tx;
            t[p * 8 + ty][tx] = (n < DMID)
                ? W1[(size_t)(k0 + p * 8 + ty) * DMID + n] : 0.0f;
        }
        __syncthreads();
#pragma unroll
        for (int p = 0; p < 4; ++p) {
            int n = n0 + p * 8 + ty;
            W1b[(size_t)n * DIN + k0 + tx] = (bf16)t[tx][p * 8 + ty];
        }
        return;
    }
    b -= CW1_BLOCKS;
    if (b < CW2_BLOCKS) {
        // W2 [1500][1024] f32 -> W2b [1024][1536] bf16 (transposed, k-pad 0)
        int n0 = (b % (DIN / 32)) * 32;
        int k0 = (b / (DIN / 32)) * 32;
        int tx = threadIdx.x & 31, ty = threadIdx.x >> 5;
#pragma unroll
        for (int p = 0; p < 4; ++p) {
            int k = k0 + p * 8 + ty;
            t[p * 8 + ty][tx] = (k < DMID)
                ? W2[(size_t)k * DIN + n0 + tx] : 0.0f;
        }
        __syncthreads();
#pragma unroll
        for (int p = 0; p < 4; ++p) {
            int n = n0 + p * 8 + ty;
            W2b[(size_t)n * DMIDP + k0 + tx] = (bf16)t[tx][p * 8 + ty];
        }
        return;
    }
    b -= CW2_BLOCKS;
    cnt[b * 256 + threadIdx.x] = 0;
}

// ---------------- CSR build + normalization ----------------
__global__ void k_count(const int* __restrict__ dst, int* cnt) {
    int e = blockIdx.x * 256 + threadIdx.x;
    atomicAdd(&cnt[dst[e]], 1);
}

// single block, 1024 threads, 16 nodes each.
// rowptr = exclusive scan of PADDED counts (pad to multiple of 8); cursor = start; isd.
__global__ __launch_bounds__(1024) void k_scan(const int* __restrict__ cnt,
                                               int* __restrict__ rowptr,
                                               int* __restrict__ cursor,
                                               float* __restrict__ isd) {
    __shared__ int sums[1024];
    int t = threadIdx.x;
    int base = t * 16;
    int v[16], p[16];
    int s = 0;
#pragma unroll
    for (int k = 0; k < 16; ++k) {
        v[k] = cnt[base + k];
        p[k] = (v[k] + 7) & ~7;  // padded row length (multiple of 8)
        s += p[k];
    }
    sums[t] = s;
    __syncthreads();
    for (int off = 1; off < 1024; off <<= 1) {
        int y = (t >= off) ? sums[t - off] : 0;
        __syncthreads();
        sums[t] += y;
        __syncthreads();
    }
    int run = sums[t] - s;  // exclusive prefix
#pragma unroll
    for (int k = 0; k < 16; ++k) {
        rowptr[base + k] = run;
        cursor[base + k] = run;
        isd[base + k] = rsqrtf((float)(v[k] + 1));  // +1 self-loop
        run += p[k];
    }
    if (t == 1023) rowptr[NN] = run;
}

// fused fill + pad (disjoint csr slots; both only need scan output)
__global__ void k_fillpad(const int* __restrict__ src, const int* __restrict__ dst,
                          int* cursor, const float* __restrict__ isd,
                          int* __restrict__ csr_src, float* __restrict__ csr_w,
                          const int* __restrict__ cnt,
                          const int* __restrict__ rowptr) {
    int b = blockIdx.x;
    if (b < NE / 256) {
        int e = b * 256 + threadIdx.x;
        int s = src[e], d = dst[e];
        int pos = atomicAdd(&cursor[d], 1);
        csr_src[pos] = s;
        csr_w[pos] = isd[s] * isd[d];
        return;
    }
    b -= NE / 256;
    int i = b * 256 + threadIdx.x;
    int c = cnt[i];
    int p = (c + 7) & ~7;
    int base = rowptr[i];
    for (int q = c; q < p; ++q) {
        csr_src[base + q] = i;    // self row: L1-hot
        csr_w[base + q] = 0.0f;   // contributes nothing
    }
}

// ---------------- GEMM: C[M,N] = A[M,K] @ Bt[N,K]^T, bf16 in / bf16 out ----------------
// R8/R10-frozen core: m97-anchor config — 128x128 tile, BK=64, single-buffered
// 32 KB LDS -> 5 blocks/CU (LDS-capped), 4 waves (2Mx2N), per-wave 64x64.
// Measured ladder: 1 blk/CU = 667 TF (R1-R6, schedule-invariant), 2 blk = 803
// (R7), 5 blk = 852 TF / MfmaUtil 35 (R8/R10). Cross-block overlap (m114) is
// the mechanism. T2 pre-swizzle (0 conflicts), width-16 gload_lds, setprio.
// __launch_bounds__(256,4): R9's (256,5) forced VGPR 60->48 < the 64 the
// accumulator needs -> scratch spill (WRITE 49->162MB, gemm 60->146us). Never
// bound waves tighter than regalloc affords; LDS caps blocks at 5 regardless.
// R11: T1 XCD chunked swizzle (bijective: nwg 1536/1024, both %8==0).
// Mechanism: bm-fast dispatch round-robins XCDs -> every XCD L2 touches all
// B-panels; chunked mapping gives each XCD a contiguous tile range -> <=2
// B-panels (3.1MB ~ L2-resident) -> per-tile B re-reads become L2 hits.
template <int K, int N, bool RELU_BIAS>
__global__ __launch_bounds__(256, 4) void gemm128(const bf16* __restrict__ A,
                                                  const bf16* __restrict__ Bt,
                                                  bf16* __restrict__ C,
                                                  const float* __restrict__ bias) {
    constexpr int NT = K / 64;
    __shared__ __align__(16) bf16 ldsA[128 * 64];  // 16 KB
    __shared__ __align__(16) bf16 ldsB[128 * 64];  // 16 KB -> 32 KB total
    const int tid = threadIdx.x;
    const int w = tid >> 6;          // 0..3
    const int lane = tid & 63;
    // T1 chunked XCD swizzle: hardware block b runs on XCD b%8; remap so each
    // XCD covers a contiguous chunk of logical tiles.
    const int nbm = gridDim.x;
    const int lin = blockIdx.y * nbm + blockIdx.x;
    const int cpx = (nbm * gridDim.y) >> 3;      // nwg/8, exact (nwg%8==0)
    const int swz = (lin & 7) * cpx + (lin >> 3);
    const int bm = swz % nbm;                    // nbm = 128 -> & 127
    const int bn = swz / nbm;
    const int fr = lane & 15, fq = lane >> 4;
    const int wm = w & 1;            // M half (64 rows)
    const int wn = w >> 1;           // N half (64 cols)
    const int sx = fr & 7;           // read-side swizzle mask

    // staging: wave w covers rows w*32..w*32+31 (4 gloads of 8 rows, A and B).
    // lane l -> row_local = l>>3; fetch global k-slot (l&7)^(l>>3) so the
    // linear LDS write lands pre-swizzled (both-sides involution, rule #21).
    const int lrow = lane >> 3;
    const int lslot = (lane & 7) ^ lrow;
    const bf16* gA = A + (size_t)(bm * 128 + w * 32 + lrow) * K + lslot * 8;
    const bf16* gB = Bt + (size_t)(bn * 128 + w * 32 + lrow) * K + lslot * 8;

    f32x4 acc[4][4];
#pragma unroll
    for (int i = 0; i < 4; ++i)
#pragma unroll
        for (int j = 0; j < 4; ++j) acc[i][j] = {0.f, 0.f, 0.f, 0.f};

    for (int t = 0; t < NT; ++t) {
#pragma unroll
        for (int r = 0; r < 4; ++r)
            gload_lds16(gA + (size_t)t * 64 + (size_t)(r * 8) * K,
                        &ldsA[0] + w * 2048 + r * 512);
#pragma unroll
        for (int r = 0; r < 4; ++r)
            gload_lds16(gB + (size_t)t * 64 + (size_t)(r * 8) * K,
                        &ldsB[0] + w * 2048 + r * 512);
        __syncthreads();  // compiler emits vmcnt(0) lgkm(0) before s_barrier (RAW)
#pragma unroll
        for (int ks = 0; ks < 2; ++ks) {
            bf16x8 bq[4], af[4];
#pragma unroll
            for (int nt = 0; nt < 4; ++nt) {
                int row = wn * 64 + nt * 16 + fr;
                int sl = ((ks << 2) | fq) ^ sx;
                bq[nt] = *(const bf16x8*)((const char*)&ldsB[0] +
                                          row * 128 + sl * 16);
            }
#pragma unroll
            for (int mt = 0; mt < 4; ++mt) {
                int row = wm * 64 + mt * 16 + fr;
                int sl = ((ks << 2) | fq) ^ sx;
                af[mt] = *(const bf16x8*)((const char*)&ldsA[0] +
                                          row * 128 + sl * 16);
            }
            __builtin_amdgcn_s_setprio(1);
#pragma unroll
            for (int mt = 0; mt < 4; ++mt)
#pragma unroll
                for (int nt = 0; nt < 4; ++nt)
                    acc[mt][nt] = __builtin_amdgcn_mfma_f32_16x16x32_bf16(
                        af[mt], bq[nt], acc[mt][nt], 0, 0, 0);
            __builtin_amdgcn_s_setprio(0);
        }
        __syncthreads();  // WAR: all reads drained before next tile's staging
    }

    // epilogue: scalar store (C/D layout verified m89/m91: col = lane&15,
    // row = (lane>>4)*4 + reg). WRITE_SIZE measured ~ideal with this pattern.
    float bv[4];
    if (RELU_BIAS) {
#pragma unroll
        for (int nt = 0; nt < 4; ++nt) {
            int col = bn * 128 + wn * 64 + nt * 16 + fr;
            bv[nt] = (col < DMID) ? bias[col] : 0.0f;
        }
    }
#pragma unroll
    for (int mq = 0; mq < 4; ++mq) {
        int row0 = bm * 128 + wm * 64 + mq * 16 + fq * 4;
#pragma unroll
        for (int nt = 0; nt < 4; ++nt) {
            int col = bn * 128 + wn * 64 + nt * 16 + fr;
#pragma unroll
            for (int r = 0; r < 4; ++r) {
                float v = acc[mq][nt][r];
                if (RELU_BIAS) v = fmaxf(v + bv[nt], 0.0f);
                C[(size_t)(row0 + r) * N + col] = (bf16)v;
            }
        }
    }
}

// ---------------- aggregation (CSR gather, barrier-free) ----------------
// R9-proven: two nodes per 256-thread block (threads 0-127 -> node 2b,
// 128-255 -> node 2b+1); per-thread body is the R4 8-gathers-in-flight loop.

// XA[i] = isd_i^2 * X[i] + sum_j w_ij * X[j], 1024-wide bf16 in/out
__global__ __launch_bounds__(256) void k_aggX(const bf16* __restrict__ X,
                                              const int* __restrict__ rowptr,
                                              const int* __restrict__ csr_src,
                                              const float* __restrict__ csr_w,
                                              const float* __restrict__ isd,
                                              bf16* __restrict__ XA) {
    int i = blockIdx.x * 2 + (threadIdx.x >> 7);
    int t = threadIdx.x & 127;     // 128 threads * 8 cols = 1024
    int c0 = t * 8;
    int beg = rowptr[i], end = rowptr[i + 1];  // uniform per half-block
    float wi = isd[i];
    float w0 = wi * wi;
    float a[8];
    bf16x8 h = *(const bf16x8*)&X[(size_t)i * DIN + c0];
#pragma unroll
    for (int k = 0; k < 8; ++k) a[k] = w0 * (float)h[k];
    for (int e = beg; e < end; e += 8) {
        int j[8];
        float w[8];
        bf16x8 hv[8];
#pragma unroll
        for (int q = 0; q < 8; ++q) { j[q] = csr_src[e + q]; w[q] = csr_w[e + q]; }
#pragma unroll
        for (int q = 0; q < 8; ++q)
            hv[q] = *(const bf16x8*)&X[(size_t)j[q] * DIN + c0];
#pragma unroll
        for (int q = 0; q < 8; ++q)
#pragma unroll
            for (int k = 0; k < 8; ++k) a[k] += w[q] * (float)hv[q][k];
    }
    bf16x8 o;
#pragma unroll
    for (int k = 0; k < 8; ++k) o[k] = (bf16)a[k];
    *(bf16x8*)&XA[(size_t)i * DIN + c0] = o;
}

// layer 2: out[i] = isd_i^2 * H[i] + sum_j w_ij * H[j] + b2, f32 out
__global__ __launch_bounds__(256) void k_agg2(const bf16* __restrict__ H,
                                              const int* __restrict__ rowptr,
                                              const int* __restrict__ csr_src,
                                              const float* __restrict__ csr_w,
                                              const float* __restrict__ isd,
                                              const float* __restrict__ b2,
                                              float* __restrict__ out) {
    int i = blockIdx.x * 2 + (threadIdx.x >> 7);
    int t = threadIdx.x & 127;
    int c0 = t * 8;
    int beg = rowptr[i], end = rowptr[i + 1];
    float wi = isd[i];
    float w0 = wi * wi;
    float a[8];
    bf16x8 h = *(const bf16x8*)&H[(size_t)i * DIN + c0];
#pragma unroll
    for (int k = 0; k < 8; ++k) a[k] = w0 * (float)h[k];
    for (int e = beg; e < end; e += 8) {
        int j[8];
        float w[8];
        bf16x8 hv[8];
#pragma unroll
        for (int q = 0; q < 8; ++q) { j[q] = csr_src[e + q]; w[q] = csr_w[e + q]; }
#pragma unroll
        for (int q = 0; q < 8; ++q)
            hv[q] = *(const bf16x8*)&H[(size_t)j[q] * DIN + c0];
#pragma unroll
        for (int q = 0; q < 8; ++q)
#pragma unroll
            for (int k = 0; k < 8; ++k) a[k] += w[q] * (float)hv[q][k];
    }
    float4 o0, o1;
    o0.x = a[0] + b2[c0 + 0]; o0.y = a[1] + b2[c0 + 1];
    o0.z = a[2] + b2[c0 + 2]; o0.w = a[3] + b2[c0 + 3];
    o1.x = a[4] + b2[c0 + 4]; o1.y = a[5] + b2[c0 + 5];
    o1.z = a[6] + b2[c0 + 6]; o1.w = a[7] + b2[c0 + 7];
    *(float4*)&out[(size_t)i * DIN + c0] = o0;
    *(float4*)&out[(size_t)i * DIN + c0 + 4] = o1;
}

extern "C" void kernel_launch(void* const* d_in, const int* in_sizes, int n_in,
                              void* d_out, int out_size, void* d_ws, size_t ws_size,
                              hipStream_t stream) {
    const float* x = (const float*)d_in[0];
    const int* ei = (const int*)d_in[1];
    const float* W1 = (const float*)d_in[2];
    const float* b1 = (const float*)d_in[3];
    const float* W2 = (const float*)d_in[4];
    const float* b2 = (const float*)d_in[5];
    float* out = (float*)d_out;
    const int* src = ei;
    const int* dst = ei + NE;

    // R11 workspace layout (94.7 MB, was 122): Y1b overlaps dead-Xb.
    // Lifetimes: Xb live prep->aggX; XA live aggX->gemm1 (then reused as H2b,
    // live gemm2->agg2); Y1b live gemm1->gemm2 and starts AT Xb's offset
    // (Xb dead once aggX completed; Y1b's extra 16.8MB is fresh space).
    char* ws = (char*)d_ws;
    int* cnt      = (int*)(ws + 0);          //  64 KB
    int* cursor   = (int*)(ws + 65536);      //  64 KB
    float* isd    = (float*)(ws + 131072);   //  64 KB
    int* rowptr   = (int*)(ws + 196608);     // 128 KB (NN+1 ints)
    int* csr_src  = (int*)(ws + 327680);     //   2 MB (padded <= 245760 entries)
    float* csr_w  = (float*)(ws + 2424832);  //   2 MB (ends 4521984)
    bf16* XA      = (bf16*)(ws + 4521984);   // 33.55 MB (ends 38076416)
    bf16* W1b     = (bf16*)(ws + 38076416);  //  3.15 MB (ends 41222144)
    bf16* W2b     = (bf16*)(ws + 41222144);  //  3.15 MB (ends 44367872)
    bf16* Xb      = (bf16*)(ws + 44367872);  // 33.55 MB (ends 77922304)
    bf16* Y1b     = (bf16*)(ws + 44367872);  // 50.33 MB over dead Xb (ends 94699520)
    bf16* H2b     = XA;                      // XA dead after GEMM1

    // 8 dispatches total: prep -> count -> scan -> fillpad ->
    // aggX -> gemm1 -> gemm2 -> agg2
    k_prep<<<PREP_BLOCKS, 256, 0, stream>>>((const float4*)x, (bf16x4*)Xb,
                                            W1, W1b, W2, W2b, cnt);
    k_count<<<NE / 256, 256, 0, stream>>>(dst, cnt);
    k_scan<<<1, 1024, 0, stream>>>(cnt, rowptr, cursor, isd);
    k_fillpad<<<NE / 256 + NN / 256, 256, 0, stream>>>(src, dst, cursor, isd,
                                                       csr_src, csr_w, cnt, rowptr);

    // layer 1: XA = A_hat @ X ; Y1 = relu(XA @ W1 + b1)   [agg commutes with linear]
    k_aggX<<<NN / 2, 256, 0, stream>>>(Xb, rowptr, csr_src, csr_w, isd, XA);
    dim3 g1(NN / 128, DMIDP / 128);   // 1536 blocks @5/CU -> 1.2 rounds (streamed)
    gemm128<DIN, DMIDP, true><<<g1, 256, 0, stream>>>(XA, W1b, Y1b, b1);

    // layer 2: H2 = Y1 @ W2 ; out = A_hat @ H2 + b2
    dim3 g2(NN / 128, DIN / 128);     // 1024 blocks @5/CU -> 0.8 round
    gemm128<DMIDP, DIN, false><<<g2, 256, 0, stream>>>(Y1b, W2b, H2b, nullptr);
    k_agg2<<<NN / 2, 256, 0, stream>>>(H2b, rowptr, csr_src, csr_w, isd, b2, out);
}

// Round 12
// 348.947 us; speedup vs baseline: 1.0886x; 1.0886x over previous
//
#include <hip/hip_runtime.h>
#include <cstdint>
#include <cstddef>

// Problem constants (fixed by the reference)
#define NN 16384      // nodes
#define DIN 1024      // hid_size
#define DMID 1500     // hidden_size (logical)
#define DMIDP 1536    // padded to multiple of 128
#define NE 131072     // edges

typedef __bf16 bf16;
typedef __bf16 bf16x4 __attribute__((ext_vector_type(4)));
typedef __bf16 bf16x8 __attribute__((ext_vector_type(8)));
typedef float f32x4 __attribute__((ext_vector_type(4)));

#define GLOBAL_AS __attribute__((address_space(1)))
#define LDS_AS __attribute__((address_space(3)))

__device__ __forceinline__ void gload_lds16(const bf16* g, bf16* l) {
    // async 16B/lane global->LDS; LDS dest is wave-uniform base + lane*16
    __builtin_amdgcn_global_load_lds((GLOBAL_AS const unsigned int*)(g),
                                     (LDS_AS unsigned int*)(l), 16, 0, 0);
}

// ---------------- fused prep: cvt_x + cvt_w1 + cvt_w2 + zero_cnt ----------------
// R9-proven: 4 independent prep kernels in one dispatch.
// R12: exact R10 form restored (R11's cvt_x grid-stride + workspace re-layout
// were part of a +7.8 us non-gemm regression; same-code noise is <1 us).
#define CVX_BLOCKS (NN * DIN / 4 / 256)          // 16384
#define CW1_BLOCKS ((DMIDP / 32) * (DIN / 32))   // 1536
#define CW2_BLOCKS ((DIN / 32) * (DMIDP / 32))   // 1536
#define ZERO_BLOCKS (NN / 256)                   // 64
#define PREP_BLOCKS (CVX_BLOCKS + CW1_BLOCKS + CW2_BLOCKS + ZERO_BLOCKS)

__global__ __launch_bounds__(256) void k_prep(const float4* __restrict__ x,
                                              bf16x4* __restrict__ xb,
                                              const float* __restrict__ W1,
                                              bf16* __restrict__ W1b,
                                              const float* __restrict__ W2,
                                              bf16* __restrict__ W2b,
                                              int* __restrict__ cnt) {
    __shared__ float t[32][33];
    int b = blockIdx.x;
    if (b < CVX_BLOCKS) {
        // cvt_x: f32 -> bf16, vectorized
        int i = b * 256 + threadIdx.x;
        float4 v = x[i];
        bf16x4 o;
        o[0] = (bf16)v.x; o[1] = (bf16)v.y; o[2] = (bf16)v.z; o[3] = (bf16)v.w;
        xb[i] = o;
        return;
    }
    b -= CVX_BLOCKS;
    if (b < CW1_BLOCKS) {
        // W1 [1024][1500] f32 -> W1b [1536][1024] bf16 (transposed, n-pad 0)
        int n0 = (b % (DMIDP / 32)) * 32;
        int k0 = (b / (DMIDP / 32)) * 32;
        int tx = threadIdx.x & 31, ty = threadIdx.x >> 5;
#pragma unroll
        for (int p = 0; p < 4; ++p) {
            int n = n0 + tx;
            t[p * 8 + ty][tx] = (n < DMID)
                ? W1[(size_t)(k0 + p * 8 + ty) * DMID + n] : 0.0f;
        }
        __syncthreads();
#pragma unroll
        for (int p = 0; p < 4; ++p) {
            int n = n0 + p * 8 + ty;
            W1b[(size_t)n * DIN + k0 + tx] = (bf16)t[tx][p * 8 + ty];
        }
        return;
    }
    b -= CW1_BLOCKS;
    if (b < CW2_BLOCKS) {
        // W2 [1500][1024] f32 -> W2b [1024][1536] bf16 (transposed, k-pad 0)
        int n0 = (b % (DIN / 32)) * 32;
        int k0 = (b / (DIN / 32)) * 32;
        int tx = threadIdx.x & 31, ty = threadIdx.x >> 5;
#pragma unroll
        for (int p = 0; p < 4; ++p) {
            int k = k0 + p * 8 + ty;
            t[p * 8 + ty][tx] = (k < DMID)
                ? W2[(size_t)k * DIN + n0 + tx] : 0.0f;
        }
        __syncthreads();
#pragma unroll
        for (int p = 0; p < 4; ++p) {
            int n = n0 + p * 8 + ty;
            W2b[(size_t)n * DMIDP + k0 + tx] = (bf16)t[tx][p * 8 + ty];
        }
        return;
    }
    b -= CW2_BLOCKS;
    cnt[b * 256 + threadIdx.x] = 0;
}

// ---------------- CSR build + normalization ----------------
__global__ void k_count(const int* __restrict__ dst, int* cnt) {
    int e = blockIdx.x * 256 + threadIdx.x;
    atomicAdd(&cnt[dst[e]], 1);
}

// single block, 1024 threads, 16 nodes each.
// rowptr = exclusive scan of PADDED counts (pad to multiple of 8); cursor = start; isd.
__global__ __launch_bounds__(1024) void k_scan(const int* __restrict__ cnt,
                                               int* __restrict__ rowptr,
                                               int* __restrict__ cursor,
                                               float* __restrict__ isd) {
    __shared__ int sums[1024];
    int t = threadIdx.x;
    int base = t * 16;
    int v[16], p[16];
    int s = 0;
#pragma unroll
    for (int k = 0; k < 16; ++k) {
        v[k] = cnt[base + k];
        p[k] = (v[k] + 7) & ~7;  // padded row length (multiple of 8)
        s += p[k];
    }
    sums[t] = s;
    __syncthreads();
    for (int off = 1; off < 1024; off <<= 1) {
        int y = (t >= off) ? sums[t - off] : 0;
        __syncthreads();
        sums[t] += y;
        __syncthreads();
    }
    int run = sums[t] - s;  // exclusive prefix
#pragma unroll
    for (int k = 0; k < 16; ++k) {
        rowptr[base + k] = run;
        cursor[base + k] = run;
        isd[base + k] = rsqrtf((float)(v[k] + 1));  // +1 self-loop
        run += p[k];
    }
    if (t == 1023) rowptr[NN] = run;
}

// fused fill + pad (disjoint csr slots; both only need scan output)
__global__ void k_fillpad(const int* __restrict__ src, const int* __restrict__ dst,
                          int* cursor, const float* __restrict__ isd,
                          int* __restrict__ csr_src, float* __restrict__ csr_w,
                          const int* __restrict__ cnt,
                          const int* __restrict__ rowptr) {
    int b = blockIdx.x;
    if (b < NE / 256) {
        int e = b * 256 + threadIdx.x;
        int s = src[e], d = dst[e];
        int pos = atomicAdd(&cursor[d], 1);
        csr_src[pos] = s;
        csr_w[pos] = isd[s] * isd[d];
        return;
    }
    b -= NE / 256;
    int i = b * 256 + threadIdx.x;
    int c = cnt[i];
    int p = (c + 7) & ~7;
    int base = rowptr[i];
    for (int q = c; q < p; ++q) {
        csr_src[base + q] = i;    // self row: L1-hot
        csr_w[base + q] = 0.0f;   // contributes nothing
    }
}

// ---------------- GEMM: C[M,N] = A[M,K] @ Bt[N,K]^T, bf16 in / bf16 out ----------------
// R8/R10-frozen: m97-anchor config — 128x128 tile, BK=64, single-buffered 32 KB
// LDS -> 5 blocks/CU (LDS-capped), 4 waves (2Mx2N), per-wave 64x64.
// Measured occupancy ladder: 1 blk/CU = 667 TF (R1-R6, schedule-invariant),
// 2 blk = 803 (R7), 5 blk = 852 TF / MfmaUtil 35 (R8/R10). Cross-block overlap
// (m114) is the mechanism; intra-block schedule is not (4 variants null).
// T2 pre-swizzle (0 conflicts), width-16 gload_lds, setprio.
// __launch_bounds__(256,4): (256,5) forced VGPR 60->48 < the 64 the acc needs
// -> scratch spill (WRITE 49->162MB, gemm 60->146us). R9 lesson.
// NO XCD remap: default bm-fast dispatch co-locates all 12 same-bm blocks on
// XCD bm%8 (128%8==0) — accidentally A-optimal. R11's chunked T1 swizzle broke
// this: FETCH 54.7->200MB, +10us/gemm. A (33-50MB) dominates B (3.1MB) here.
template <int K, int N, bool RELU_BIAS>
__global__ __launch_bounds__(256, 4) void gemm128(const bf16* __restrict__ A,
                                                  const bf16* __restrict__ Bt,
                                                  bf16* __restrict__ C,
                                                  const float* __restrict__ bias) {
    constexpr int NT = K / 64;
    __shared__ __align__(16) bf16 ldsA[128 * 64];  // 16 KB
    __shared__ __align__(16) bf16 ldsB[128 * 64];  // 16 KB -> 32 KB total
    const int tid = threadIdx.x;
    const int w = tid >> 6;          // 0..3
    const int lane = tid & 63;
    const int bm = blockIdx.x, bn = blockIdx.y;
    const int fr = lane & 15, fq = lane >> 4;
    const int wm = w & 1;            // M half (64 rows)
    const int wn = w >> 1;           // N half (64 cols)
    const int sx = fr & 7;           // read-side swizzle mask

    // staging: wave w covers rows w*32..w*32+31 (4 gloads of 8 rows, A and B).
    // lane l -> row_local = l>>3; fetch global k-slot (l&7)^(l>>3) so the
    // linear LDS write lands pre-swizzled (both-sides involution, rule #21).
    const int lrow = lane >> 3;
    const int lslot = (lane & 7) ^ lrow;
    const bf16* gA = A + (size_t)(bm * 128 + w * 32 + lrow) * K + lslot * 8;
    const bf16* gB = Bt + (size_t)(bn * 128 + w * 32 + lrow) * K + lslot * 8;

    f32x4 acc[4][4];
#pragma unroll
    for (int i = 0; i < 4; ++i)
#pragma unroll
        for (int j = 0; j < 4; ++j) acc[i][j] = {0.f, 0.f, 0.f, 0.f};

    for (int t = 0; t < NT; ++t) {
#pragma unroll
        for (int r = 0; r < 4; ++r)
            gload_lds16(gA + (size_t)t * 64 + (size_t)(r * 8) * K,
                        &ldsA[0] + w * 2048 + r * 512);
#pragma unroll
        for (int r = 0; r < 4; ++r)
            gload_lds16(gB + (size_t)t * 64 + (size_t)(r * 8) * K,
                        &ldsB[0] + w * 2048 + r * 512);
        __syncthreads();  // compiler emits vmcnt(0) lgkm(0) before s_barrier (RAW)
#pragma unroll
        for (int ks = 0; ks < 2; ++ks) {
            bf16x8 bq[4], af[4];
#pragma unroll
            for (int nt = 0; nt < 4; ++nt) {
                int row = wn * 64 + nt * 16 + fr;
                int sl = ((ks << 2) | fq) ^ sx;
                bq[nt] = *(const bf16x8*)((const char*)&ldsB[0] +
                                          row * 128 + sl * 16);
            }
#pragma unroll
            for (int mt = 0; mt < 4; ++mt) {
                int row = wm * 64 + mt * 16 + fr;
                int sl = ((ks << 2) | fq) ^ sx;
                af[mt] = *(const bf16x8*)((const char*)&ldsA[0] +
                                          row * 128 + sl * 16);
            }
            __builtin_amdgcn_s_setprio(1);
#pragma unroll
            for (int mt = 0; mt < 4; ++mt)
#pragma unroll
                for (int nt = 0; nt < 4; ++nt)
                    acc[mt][nt] = __builtin_amdgcn_mfma_f32_16x16x32_bf16(
                        af[mt], bq[nt], acc[mt][nt], 0, 0, 0);
            __builtin_amdgcn_s_setprio(0);
        }
        __syncthreads();  // WAR: all reads drained before next tile's staging
    }

    // epilogue: scalar store (C/D layout verified m89/m91: col = lane&15,
    // row = (lane>>4)*4 + reg). WRITE_SIZE measured ~ideal with this pattern.
    float bv[4];
    if (RELU_BIAS) {
#pragma unroll
        for (int nt = 0; nt < 4; ++nt) {
            int col = bn * 128 + wn * 64 + nt * 16 + fr;
            bv[nt] = (col < DMID) ? bias[col] : 0.0f;
        }
    }
#pragma unroll
    for (int mq = 0; mq < 4; ++mq) {
        int row0 = bm * 128 + wm * 64 + mq * 16 + fq * 4;
#pragma unroll
        for (int nt = 0; nt < 4; ++nt) {
            int col = bn * 128 + wn * 64 + nt * 16 + fr;
#pragma unroll
            for (int r = 0; r < 4; ++r) {
                float v = acc[mq][nt][r];
                if (RELU_BIAS) v = fmaxf(v + bv[nt], 0.0f);
                C[(size_t)(row0 + r) * N + col] = (bf16)v;
            }
        }
    }
}

// ---------------- aggregation (CSR gather, barrier-free) ----------------
// R9-proven: two nodes per 256-thread block (threads 0-127 -> node 2b,
// 128-255 -> node 2b+1); per-thread body is the R4 8-gathers-in-flight loop.

// XA[i] = isd_i^2 * X[i] + sum_j w_ij * X[j], 1024-wide bf16 in/out
__global__ __launch_bounds__(256) void k_aggX(const bf16* __restrict__ X,
                                              const int* __restrict__ rowptr,
                                              const int* __restrict__ csr_src,
                                              const float* __restrict__ csr_w,
                                              const float* __restrict__ isd,
                                              bf16* __restrict__ XA) {
    int i = blockIdx.x * 2 + (threadIdx.x >> 7);
    int t = threadIdx.x & 127;     // 128 threads * 8 cols = 1024
    int c0 = t * 8;
    int beg = rowptr[i], end = rowptr[i + 1];  // uniform per half-block
    float wi = isd[i];
    float w0 = wi * wi;
    float a[8];
    bf16x8 h = *(const bf16x8*)&X[(size_t)i * DIN + c0];
#pragma unroll
    for (int k = 0; k < 8; ++k) a[k] = w0 * (float)h[k];
    for (int e = beg; e < end; e += 8) {
        int j[8];
        float w[8];
        bf16x8 hv[8];
#pragma unroll
        for (int q = 0; q < 8; ++q) { j[q] = csr_src[e + q]; w[q] = csr_w[e + q]; }
#pragma unroll
        for (int q = 0; q < 8; ++q)
            hv[q] = *(const bf16x8*)&X[(size_t)j[q] * DIN + c0];
#pragma unroll
        for (int q = 0; q < 8; ++q)
#pragma unroll
            for (int k = 0; k < 8; ++k) a[k] += w[q] * (float)hv[q][k];
    }
    bf16x8 o;
#pragma unroll
    for (int k = 0; k < 8; ++k) o[k] = (bf16)a[k];
    *(bf16x8*)&XA[(size_t)i * DIN + c0] = o;
}

// layer 2: out[i] = isd_i^2 * H[i] + sum_j w_ij * H[j] + b2, f32 out
__global__ __launch_bounds__(256) void k_agg2(const bf16* __restrict__ H,
                                              const int* __restrict__ rowptr,
                                              const int* __restrict__ csr_src,
                                              const float* __restrict__ csr_w,
                                              const float* __restrict__ isd,
                                              const float* __restrict__ b2,
                                              float* __restrict__ out) {
    int i = blockIdx.x * 2 + (threadIdx.x >> 7);
    int t = threadIdx.x & 127;
    int c0 = t * 8;
    int beg = rowptr[i], end = rowptr[i + 1];
    float wi = isd[i];
    float w0 = wi * wi;
    float a[8];
    bf16x8 h = *(const bf16x8*)&H[(size_t)i * DIN + c0];
#pragma unroll
    for (int k = 0; k < 8; ++k) a[k] = w0 * (float)h[k];
    for (int e = beg; e < end; e += 8) {
        int j[8];
        float w[8];
        bf16x8 hv[8];
#pragma unroll
        for (int q = 0; q < 8; ++q) { j[q] = csr_src[e + q]; w[q] = csr_w[e + q]; }
#pragma unroll
        for (int q = 0; q < 8; ++q)
            hv[q] = *(const bf16x8*)&H[(size_t)j[q] * DIN + c0];
#pragma unroll
        for (int q = 0; q < 8; ++q)
#pragma unroll
            for (int k = 0; k < 8; ++k) a[k] += w[q] * (float)hv[q][k];
    }
    float4 o0, o1;
    o0.x = a[0] + b2[c0 + 0]; o0.y = a[1] + b2[c0 + 1];
    o0.z = a[2] + b2[c0 + 2]; o0.w = a[3] + b2[c0 + 3];
    o1.x = a[4] + b2[c0 + 4]; o1.y = a[5] + b2[c0 + 5];
    o1.z = a[6] + b2[c0 + 6]; o1.w = a[7] + b2[c0 + 7];
    *(float4*)&out[(size_t)i * DIN + c0] = o0;
    *(float4*)&out[(size_t)i * DIN + c0 + 4] = o1;
}

extern "C" void kernel_launch(void* const* d_in, const int* in_sizes, int n_in,
                              void* d_out, int out_size, void* d_ws, size_t ws_size,
                              hipStream_t stream) {
    const float* x = (const float*)d_in[0];
    const int* ei = (const int*)d_in[1];
    const float* W1 = (const float*)d_in[2];
    const float* b1 = (const float*)d_in[3];
    const float* W2 = (const float*)d_in[4];
    const float* b2 = (const float*)d_in[5];
    float* out = (float*)d_out;
    const int* src = ei;
    const int* dst = ei + NE;

    // workspace layout (bytes), total ~122 MB (R10-exact)
    char* ws = (char*)d_ws;
    int* cnt      = (int*)(ws + 0);          //  64 KB
    int* cursor   = (int*)(ws + 65536);      //  64 KB
    float* isd    = (float*)(ws + 131072);   //  64 KB
    int* rowptr   = (int*)(ws + 196608);     // 128 KB (NN+1 ints)
    int* csr_src  = (int*)(ws + 327680);     //   2 MB (padded <= 245760 entries)
    float* csr_w  = (float*)(ws + 2424832);  //   2 MB
    bf16* Xb      = (bf16*)(ws + 4521984);   // 33.55 MB (16384x1024)
    bf16* XA      = (bf16*)(ws + 38076416);  // 33.55 MB — reused as H2b
    bf16* W1b     = (bf16*)(ws + 71630848);  //  3.15 MB (1536x1024, transposed)
    bf16* W2b     = (bf16*)(ws + 74776576);  //  3.15 MB (1024x1536, transposed)
    bf16* Y1b     = (bf16*)(ws + 77922304);  // 50.33 MB (16384x1536)
    bf16* H2b     = XA;                      // XA dead after GEMM1

    // 8 dispatches total: prep -> count -> scan -> fillpad ->
    // aggX -> gemm1 -> gemm2 -> agg2
    k_prep<<<PREP_BLOCKS, 256, 0, stream>>>((const float4*)x, (bf16x4*)Xb,
                                            W1, W1b, W2, W2b, cnt);
    k_count<<<NE / 256, 256, 0, stream>>>(dst, cnt);
    k_scan<<<1, 1024, 0, stream>>>(cnt, rowptr, cursor, isd);
    k_fillpad<<<NE / 256 + NN / 256, 256, 0, stream>>>(src, dst, cursor, isd,
                                                       csr_src, csr_w, cnt, rowptr);

    // layer 1: XA = A_hat @ X ; Y1 = relu(XA @ W1 + b1)   [agg commutes with linear]
    k_aggX<<<NN / 2, 256, 0, stream>>>(Xb, rowptr, csr_src, csr_w, isd, XA);
    dim3 g1(NN / 128, DMIDP / 128);   // 1536 blocks @5/CU -> 1.2 rounds (streamed)
    gemm128<DIN, DMIDP, true><<<g1, 256, 0, stream>>>(XA, W1b, Y1b, b1);

    // layer 2: H2 = Y1 @ W2 ; out = A_hat @ H2 + b2
    dim3 g2(NN / 128, DIN / 128);     // 1024 blocks @5/CU -> 0.8 round
    gemm128<DMIDP, DIN, false><<<g2, 256, 0, stream>>>(Y1b, W2b, H2b, nullptr);
    k_agg2<<<NN / 2, 256, 0, stream>>>(H2b, rowptr, csr_src, csr_w, isd, b2, out);
}